// Round 1
// baseline (216.933 us; speedup 1.0000x reference)
//
#include <hip/hip_runtime.h>
#include <hip/hip_bf16.h>

// RelationCos pipeline: FPS -> KNN(x2) -> gather -> (1x1 conv + BN + ReLU + max over k)
// B=16, N=8192, S=32, K=12, D_s=256, D_t=1024, D_out=1024.
// GEMMs run as bf16 MFMA (16x16x32), everything index-critical (FPS/KNN) in exact f32
// with fp-contract off to match the numpy/jax reference's tie behavior.
//
// Workspace layout (assumes ws_size >= ~19 MB):
//   [0)       new_xyz  float[16*32*3]
//   [8192)    idx_s    int[16*32*12]
//   [32768)   idx_t    int[16*32*12]
//   [57344)   Wb_s     bf16[1024*256]
//   [581632)  Wb_t     bf16[1024*1024]
//   [2678784) A        bf16[8192*1024]   (reused: s-pass then t-pass)

#define NPTS 8192
#define BATCH 16
#define SPTS 32
#define KNN_K 12
#define DS 256
#define DT 1024
#define DOUT 1024

typedef float f32x4 __attribute__((ext_vector_type(4)));
typedef __bf16 bf16x8 __attribute__((ext_vector_type(8)));
typedef unsigned short ushort_t;

__device__ __forceinline__ ushort_t f2bf(float f) {
    unsigned int u = __float_as_uint(f);
    u += 0x7fffu + ((u >> 16) & 1u);   // RNE
    return (ushort_t)(u >> 16);
}

// ---------------- W -> bf16 convert ----------------
__global__ void convw_kernel(const float* __restrict__ W, ushort_t* __restrict__ Wb, int n4) {
    int i = blockIdx.x * blockDim.x + threadIdx.x;
    if (i < n4) {
        float4 v = reinterpret_cast<const float4*>(W)[i];
        ushort4 u;
        u.x = f2bf(v.x); u.y = f2bf(v.y); u.z = f2bf(v.z); u.w = f2bf(v.w);
        reinterpret_cast<ushort4*>(Wb)[i] = u;
    }
}

// ---------------- FPS ----------------
// 1 block per batch, 1024 threads; each thread owns 8 points in registers.
__global__ __launch_bounds__(1024) void fps_kernel(const float* __restrict__ xyz,
                                                   float* __restrict__ new_xyz) {
#pragma clang fp contract(off)
    int b = blockIdx.x;
    int tid = threadIdx.x;
    const float* base = xyz + (size_t)b * NPTS * 3;

    float px[8], py[8], pz[8], dd[8];
#pragma unroll
    for (int i = 0; i < 8; ++i) {
        int p = tid + i * 1024;
        px[i] = base[p * 3 + 0];
        py[i] = base[p * 3 + 1];
        pz[i] = base[p * 3 + 2];
        dd[i] = 1e10f;
    }

    __shared__ float rv[16];
    __shared__ int ri[16];
    __shared__ int scur;

    if (tid == 0) {
        new_xyz[((size_t)b * SPTS + 0) * 3 + 0] = base[0];
        new_xyz[((size_t)b * SPTS + 0) * 3 + 1] = base[1];
        new_xyz[((size_t)b * SPTS + 0) * 3 + 2] = base[2];
    }

    int cur = 0;
    for (int it = 1; it < SPTS; ++it) {
        float lx = base[cur * 3 + 0];
        float ly = base[cur * 3 + 1];
        float lz = base[cur * 3 + 2];
        float bv = -1.0f;
        int bi = NPTS;
#pragma unroll
        for (int i = 0; i < 8; ++i) {
            float dx = px[i] - lx, dy = py[i] - ly, dz = pz[i] - lz;
            float d = dx * dx + dy * dy;
            d = d + dz * dz;
            float nd = fminf(dd[i], d);
            dd[i] = nd;
            if (nd > bv) { bv = nd; bi = tid + i * 1024; }  // strict > : first occurrence
        }
        // wave argmax (value desc, index asc on ties)
#pragma unroll
        for (int off = 1; off < 64; off <<= 1) {
            float ov = __shfl_xor(bv, off);
            int oi = __shfl_xor(bi, off);
            if (ov > bv || (ov == bv && oi < bi)) { bv = ov; bi = oi; }
        }
        int wid = tid >> 6, lane = tid & 63;
        if (lane == 0) { rv[wid] = bv; ri[wid] = bi; }
        __syncthreads();
        if (wid == 0) {
            float v = (lane < 16) ? rv[lane] : -1.0f;
            int ii = (lane < 16) ? ri[lane] : NPTS;
#pragma unroll
            for (int off = 1; off < 16; off <<= 1) {
                float ov = __shfl_xor(v, off);
                int oi = __shfl_xor(ii, off);
                if (ov > v || (ov == v && oi < ii)) { v = ov; ii = oi; }
            }
            if (lane == 0) {
                scur = ii;
                new_xyz[((size_t)b * SPTS + it) * 3 + 0] = base[ii * 3 + 0];
                new_xyz[((size_t)b * SPTS + it) * 3 + 1] = base[ii * 3 + 1];
                new_xyz[((size_t)b * SPTS + it) * 3 + 2] = base[ii * 3 + 2];
            }
        }
        __syncthreads();
        cur = scur;
    }
}

// ---------------- KNN ----------------
// grid (512 queries, 2 sets), 1 wave per block. Per-lane register top-12 + wave merge.
__global__ __launch_bounds__(64) void knn_kernel(const float* __restrict__ xyz_s,
                                                 const float* __restrict__ xyz_t,
                                                 const float* __restrict__ new_xyz,
                                                 int* __restrict__ idx_s,
                                                 int* __restrict__ idx_t) {
#pragma clang fp contract(off)
    int q = blockIdx.x;
    int set = blockIdx.y;  // 0 = s, 1 = t
    int lane = threadIdx.x;
    int b = q >> 5;
    const float* pts = (set ? xyz_t : xyz_s) + (size_t)b * NPTS * 3;
    int* out = (set ? idx_t : idx_s) + q * KNN_K;

    float q0 = new_xyz[q * 3 + 0];
    float q1 = new_xyz[q * 3 + 1];
    float q2 = new_xyz[q * 3 + 2];
    float qq = q0 * q0 + q1 * q1;
    qq = qq + q2 * q2;

    float bd[12];
    int bi[12];
#pragma unroll
    for (int j = 0; j < 12; ++j) { bd[j] = 1e30f; bi[j] = 0x7fffffff; }

    for (int i = 0; i < NPTS / 64; ++i) {
        int p = lane + i * 64;
        float p0 = pts[p * 3 + 0], p1 = pts[p * 3 + 1], p2 = pts[p * 3 + 2];
        float pp = p0 * p0 + p1 * p1; pp = pp + p2 * p2;
        float dot = q0 * p0 + q1 * p1; dot = dot + q2 * p2;
        float d = (qq - 2.0f * dot) + pp;  // reference's expanded form
        if (d < bd[11]) {
            // branch-free register insertion sort (all static indices)
#pragma unroll
            for (int j = 11; j > 0; --j) {
                bool keep = (d >= bd[j]);
                float sh = (d >= bd[j - 1]) ? d : bd[j - 1];
                int si = (d >= bd[j - 1]) ? p : bi[j - 1];
                bd[j] = keep ? bd[j] : sh;
                bi[j] = keep ? bi[j] : si;
            }
            if (d < bd[0]) { bd[0] = d; bi[0] = p; }
        }
    }

    // 12 rounds of lexicographic wave arg-min
    for (int r = 0; r < KNN_K; ++r) {
        float cv = bd[0];
        int ci = bi[0];
#pragma unroll
        for (int off = 1; off < 64; off <<= 1) {
            float ov = __shfl_xor(cv, off);
            int oi = __shfl_xor(ci, off);
            if (ov < cv || (ov == cv && oi < ci)) { cv = ov; ci = oi; }
        }
        if (lane == 0) out[r] = ci;
        if (ci == bi[0]) {  // winner lane pops its head (indices are unique)
#pragma unroll
            for (int j = 0; j < 11; ++j) { bd[j] = bd[j + 1]; bi[j] = bi[j + 1]; }
            bd[11] = 1e30f;
            bi[11] = 0x7fffffff;
        }
    }
}

// ---------------- gather -> bf16 A matrix ----------------
// A is [512 points * 16 rows][D]; rows 12..15 of each point zeroed.
__global__ __launch_bounds__(64) void gather_kernel(const float* __restrict__ feat,
                                                    const int* __restrict__ idx,
                                                    ushort_t* __restrict__ A, int D) {
    int row = blockIdx.x;  // 0..8191
    int p = row >> 4, k = row & 15;
    int tid = threadIdx.x;
    int n4 = D >> 2;
    ushort4* a4 = reinterpret_cast<ushort4*>(A + (size_t)row * D);
    if (k < KNN_K) {
        int src = idx[p * KNN_K + k];
        int b = p >> 5;
        const float4* f4 = reinterpret_cast<const float4*>(feat + ((size_t)b * NPTS + src) * D);
        for (int j = tid; j < n4; j += 64) {
            float4 v = f4[j];
            ushort4 u;
            u.x = f2bf(v.x); u.y = f2bf(v.y); u.z = f2bf(v.z); u.w = f2bf(v.w);
            a4[j] = u;
        }
    } else {
        ushort4 z; z.x = 0; z.y = 0; z.z = 0; z.w = 0;
        for (int j = tid; j < n4; j += 64) a4[j] = z;
    }
}

// ---------------- MFMA GEMM + BN/ReLU/max epilogue ----------------
// Block: 4 waves; M-tile = 8 points (128 rows), N-tile = 256 (64 per wave).
// A frag: lane holds A[m=lane&15][k=(lane>>4)*8+e]; B frag: W[o=lane&15][same k] (B=W^T).
// C/D: col=lane&15, row=(lane>>4)*4+reg (m89-verified). Pad rows 12..15 excluded via -inf.
template <int KD>
__global__ __launch_bounds__(256) void gemm_kernel(const ushort_t* __restrict__ A,
                                                   const ushort_t* __restrict__ Wb,
                                                   const float* __restrict__ bias,
                                                   const float* __restrict__ gamma,
                                                   const float* __restrict__ beta,
                                                   const float* __restrict__ mean,
                                                   const float* __restrict__ var,
                                                   float* __restrict__ out) {
    int tid = threadIdx.x;
    int w = tid >> 6, lane = tid & 63;
    int p0 = blockIdx.x * 8;
    int o_wave = blockIdx.y * 256 + w * 64;
    int lrow = lane & 15, kgrp = lane >> 4;

    f32x4 acc[8][4];
#pragma unroll
    for (int mi = 0; mi < 8; ++mi)
#pragma unroll
        for (int ni = 0; ni < 4; ++ni) {
            f32x4 z = {0.f, 0.f, 0.f, 0.f};
            acc[mi][ni] = z;
        }

    for (int kk = 0; kk < KD / 32; ++kk) {
        int k0 = kk * 32;
        bf16x8 a[8];
#pragma unroll
        for (int mi = 0; mi < 8; ++mi) {
            const ushort_t* ap = A + ((size_t)(p0 + mi) * 16 + lrow) * KD + k0 + kgrp * 8;
            a[mi] = *reinterpret_cast<const bf16x8*>(ap);
        }
#pragma unroll
        for (int ni = 0; ni < 4; ++ni) {
            const ushort_t* bp = Wb + (size_t)(o_wave + ni * 16 + lrow) * KD + k0 + kgrp * 8;
            bf16x8 bf = *reinterpret_cast<const bf16x8*>(bp);
#pragma unroll
            for (int mi = 0; mi < 8; ++mi)
                acc[mi][ni] = __builtin_amdgcn_mfma_f32_16x16x32_bf16(a[mi], bf, acc[mi][ni], 0, 0, 0);
        }
    }

    // epilogue: y = acc*sc + shift ; relu ; max over rows 0..11 ; store
#pragma unroll
    for (int ni = 0; ni < 4; ++ni) {
        int o = o_wave + ni * 16 + lrow;
        float sc = gamma[o] / sqrtf(var[o] + 1e-5f);
        float sh = (bias[o] - mean[o]) * sc + beta[o];
#pragma unroll
        for (int mi = 0; mi < 8; ++mi) {
            float m;
            if (kgrp < 3) {
                float y0 = fmaxf(acc[mi][ni][0] * sc + sh, 0.0f);
                float y1 = fmaxf(acc[mi][ni][1] * sc + sh, 0.0f);
                float y2 = fmaxf(acc[mi][ni][2] * sc + sh, 0.0f);
                float y3 = fmaxf(acc[mi][ni][3] * sc + sh, 0.0f);
                m = fmaxf(fmaxf(y0, y1), fmaxf(y2, y3));
            } else {
                m = -1e30f;  // pad rows 12..15
            }
            m = fmaxf(m, __shfl_xor(m, 16));
            m = fmaxf(m, __shfl_xor(m, 32));
            if (kgrp == 0) out[(size_t)(p0 + mi) * DOUT + o] = m;
        }
    }
}

extern "C" void kernel_launch(void* const* d_in, const int* in_sizes, int n_in,
                              void* d_out, int out_size, void* d_ws, size_t ws_size,
                              hipStream_t stream) {
    const float* feature_s = (const float*)d_in[0];
    const float* xyz_s     = (const float*)d_in[1];
    const float* feature_t = (const float*)d_in[2];
    const float* xyz_t     = (const float*)d_in[3];
    const float* Ws        = (const float*)d_in[4];
    const float* bias_s    = (const float*)d_in[5];
    const float* gamma_s   = (const float*)d_in[6];
    const float* beta_s    = (const float*)d_in[7];
    const float* mean_s    = (const float*)d_in[8];
    const float* var_s     = (const float*)d_in[9];
    const float* Wt        = (const float*)d_in[10];
    const float* bias_t    = (const float*)d_in[11];
    const float* gamma_t   = (const float*)d_in[12];
    const float* beta_t    = (const float*)d_in[13];
    const float* mean_t    = (const float*)d_in[14];
    const float* var_t     = (const float*)d_in[15];
    float* out = (float*)d_out;

    char* ws = (char*)d_ws;
    float* new_xyz  = (float*)(ws + 0);
    int* idx_s      = (int*)(ws + 8192);
    int* idx_t      = (int*)(ws + 32768);
    ushort_t* Wb_s  = (ushort_t*)(ws + 57344);
    ushort_t* Wb_t  = (ushort_t*)(ws + 581632);
    ushort_t* A     = (ushort_t*)(ws + 2678784);

    convw_kernel<<<1024, 256, 0, stream>>>(Wt, Wb_t, (1024 * 1024) / 4);
    convw_kernel<<<256, 256, 0, stream>>>(Ws, Wb_s, (1024 * 256) / 4);
    fps_kernel<<<16, 1024, 0, stream>>>(xyz_t, new_xyz);
    knn_kernel<<<dim3(512, 2), 64, 0, stream>>>(xyz_s, xyz_t, new_xyz, idx_s, idx_t);

    gather_kernel<<<8192, 64, 0, stream>>>(feature_s, idx_s, A, DS);
    gemm_kernel<DS><<<dim3(64, 4), 256, 0, stream>>>(A, Wb_s, bias_s, gamma_s, beta_s,
                                                     mean_s, var_s, out);
    gather_kernel<<<8192, 64, 0, stream>>>(feature_t, idx_t, A, DT);
    gemm_kernel<DT><<<dim3(64, 4), 256, 0, stream>>>(A, Wb_t, bias_t, gamma_t, beta_t,
                                                     mean_t, var_t, out + (size_t)512 * 1024);
}

// Round 2
// 189.368 us; speedup vs baseline: 1.1456x; 1.1456x over previous
//
#include <hip/hip_runtime.h>
#include <hip/hip_bf16.h>

// RelationCos pipeline: FPS -> KNN(x2) -> gather -> (1x1 conv + BN + ReLU + max over k)
// B=16, N=8192, S=32, K=12, D_s=256, D_t=1024, D_out=1024.
// Round 2: latency-optimized FPS (register-resident, coord-carrying shuffle argmax,
// zero global loads in the loop) and 4-wave KNN (2048 pts/wave + LDS merge).

#define NPTS 8192
#define BATCH 16
#define SPTS 32
#define KNN_K 12
#define DS 256
#define DT 1024
#define DOUT 1024

typedef float f32x4 __attribute__((ext_vector_type(4)));
typedef __bf16 bf16x8 __attribute__((ext_vector_type(8)));
typedef unsigned short ushort_t;

__device__ __forceinline__ ushort_t f2bf(float f) {
    unsigned int u = __float_as_uint(f);
    u += 0x7fffu + ((u >> 16) & 1u);   // RNE
    return (ushort_t)(u >> 16);
}

// ---------------- W -> bf16 convert ----------------
__global__ void convw_kernel(const float* __restrict__ W, ushort_t* __restrict__ Wb, int n4) {
    int i = blockIdx.x * blockDim.x + threadIdx.x;
    if (i < n4) {
        float4 v = reinterpret_cast<const float4*>(W)[i];
        ushort4 u;
        u.x = f2bf(v.x); u.y = f2bf(v.y); u.z = f2bf(v.z); u.w = f2bf(v.w);
        reinterpret_cast<ushort4*>(Wb)[i] = u;
    }
}

// ---------------- FPS ----------------
// 1 block per batch, 512 threads (8 waves), 16 points per lane in registers.
// Winner coords ride along in the shuffle argmax -> no global loads in the loop.
__global__ __launch_bounds__(512) void fps_kernel(const float* __restrict__ xyz,
                                                  float* __restrict__ new_xyz) {
#pragma clang fp contract(off)
    int b = blockIdx.x;
    int tid = threadIdx.x;
    const float* base = xyz + (size_t)b * NPTS * 3;

    float px[16], py[16], pz[16], dd[16];
#pragma unroll
    for (int i = 0; i < 16; ++i) {
        int p = tid + i * 512;
        px[i] = base[p * 3 + 0];
        py[i] = base[p * 3 + 1];
        pz[i] = base[p * 3 + 2];
        dd[i] = 1e10f;
    }

    __shared__ float rv[8], rx[8], ry[8], rz[8];
    __shared__ int ri[8];

    float lx = base[0], ly = base[1], lz = base[2];
    if (tid == 0) {
        new_xyz[((size_t)b * SPTS + 0) * 3 + 0] = lx;
        new_xyz[((size_t)b * SPTS + 0) * 3 + 1] = ly;
        new_xyz[((size_t)b * SPTS + 0) * 3 + 2] = lz;
    }

    int w = tid >> 6, lane = tid & 63;
    for (int it = 1; it < SPTS; ++it) {
        float bv = -1.0f, bx = 0.f, by = 0.f, bz = 0.f;
        int bi = NPTS;
#pragma unroll
        for (int i = 0; i < 16; ++i) {
            float dx = px[i] - lx, dy = py[i] - ly, dz = pz[i] - lz;
            float d = dx * dx + dy * dy;
            d = d + dz * dz;
            float nd = fminf(dd[i], d);
            dd[i] = nd;
            bool t = nd > bv;  // strict > : first occurrence (in-lane index ascending)
            bv = t ? nd : bv;
            bi = t ? (tid + i * 512) : bi;
            bx = t ? px[i] : bx;
            by = t ? py[i] : by;
            bz = t ? pz[i] : bz;
        }
        // wave argmax (value desc, index asc on ties), coords carried along
#pragma unroll
        for (int off = 1; off < 64; off <<= 1) {
            float ov = __shfl_xor(bv, off);
            int oi = __shfl_xor(bi, off);
            float ox = __shfl_xor(bx, off);
            float oy = __shfl_xor(by, off);
            float oz = __shfl_xor(bz, off);
            bool t = (ov > bv) || (ov == bv && oi < bi);
            bv = t ? ov : bv; bi = t ? oi : bi;
            bx = t ? ox : bx; by = t ? oy : by; bz = t ? oz : bz;
        }
        if (lane == 0) { rv[w] = bv; ri[w] = bi; rx[w] = bx; ry[w] = by; rz[w] = bz; }
        __syncthreads();
        // every thread reduces the 8 wave candidates (redundant; no 2nd broadcast step)
        float nv = rv[0]; int nidx = ri[0];
        float nx = rx[0], ny = ry[0], nz = rz[0];
#pragma unroll
        for (int w2 = 1; w2 < 8; ++w2) {
            float v2 = rv[w2]; int i2 = ri[w2];
            bool t = (v2 > nv) || (v2 == nv && i2 < nidx);
            nv = t ? v2 : nv; nidx = t ? i2 : nidx;
            nx = t ? rx[w2] : nx; ny = t ? ry[w2] : ny; nz = t ? rz[w2] : nz;
        }
        lx = nx; ly = ny; lz = nz;
        if (tid == 0) {
            new_xyz[((size_t)b * SPTS + it) * 3 + 0] = nx;
            new_xyz[((size_t)b * SPTS + it) * 3 + 1] = ny;
            new_xyz[((size_t)b * SPTS + it) * 3 + 2] = nz;
        }
        __syncthreads();  // protect LDS candidates before next iteration's writes
    }
}

// ---------------- KNN ----------------
// grid (512 queries, 2 sets), 4 waves per block; each wave scans a disjoint 2048-pt
// range (per-lane register top-12 + 12-round lex-min pop), then 48-candidate LDS merge.
__global__ __launch_bounds__(256) void knn_kernel(const float* __restrict__ xyz_s,
                                                  const float* __restrict__ xyz_t,
                                                  const float* __restrict__ new_xyz,
                                                  int* __restrict__ idx_s,
                                                  int* __restrict__ idx_t) {
#pragma clang fp contract(off)
    int q = blockIdx.x;
    int set = blockIdx.y;  // 0 = s, 1 = t
    int tid = threadIdx.x;
    int w = tid >> 6, lane = tid & 63;
    int b = q >> 5;
    const float* pts = (set ? xyz_t : xyz_s) + (size_t)b * NPTS * 3;
    int* out = (set ? idx_t : idx_s) + q * KNN_K;

    float q0 = new_xyz[q * 3 + 0];
    float q1 = new_xyz[q * 3 + 1];
    float q2 = new_xyz[q * 3 + 2];
    float qq = q0 * q0 + q1 * q1;
    qq = qq + q2 * q2;

    float bd[12];
    int bi[12];
#pragma unroll
    for (int j = 0; j < 12; ++j) { bd[j] = 1e30f; bi[j] = 0x7fffffff; }

    for (int i = 0; i < 2048 / 64; ++i) {
        int p = w * 2048 + i * 64 + lane;  // in-lane ascending global index
        float p0 = pts[p * 3 + 0], p1 = pts[p * 3 + 1], p2 = pts[p * 3 + 2];
        float pp = p0 * p0 + p1 * p1; pp = pp + p2 * p2;
        float dot = q0 * p0 + q1 * p1; dot = dot + q2 * p2;
        float d = (qq - 2.0f * dot) + pp;  // reference's expanded form
        if (d < bd[11]) {
            // branch-free register insertion sort (all static indices)
#pragma unroll
            for (int j = 11; j > 0; --j) {
                bool keep = (d >= bd[j]);
                float sh = (d >= bd[j - 1]) ? d : bd[j - 1];
                int si_ = (d >= bd[j - 1]) ? p : bi[j - 1];
                bd[j] = keep ? bd[j] : sh;
                bi[j] = keep ? bi[j] : si_;
            }
            if (d < bd[0]) { bd[0] = d; bi[0] = p; }
        }
    }

    __shared__ float sd[48];
    __shared__ int si[48];

    // per-wave: 12 rounds of lexicographic wave arg-min -> sorted 12 into LDS
#pragma unroll
    for (int r = 0; r < KNN_K; ++r) {
        float cv = bd[0];
        int ci = bi[0];
#pragma unroll
        for (int off = 1; off < 64; off <<= 1) {
            float ov = __shfl_xor(cv, off);
            int oi = __shfl_xor(ci, off);
            if (ov < cv || (ov == cv && oi < ci)) { cv = ov; ci = oi; }
        }
        if (lane == 0) { sd[w * KNN_K + r] = cv; si[w * KNN_K + r] = ci; }
        if (ci == bi[0]) {  // winner lane pops its head (indices unique within wave range)
#pragma unroll
            for (int j = 0; j < 11; ++j) { bd[j] = bd[j + 1]; bi[j] = bi[j + 1]; }
            bd[11] = 1e30f;
            bi[11] = 0x7fffffff;
        }
    }
    __syncthreads();

    // wave 0: merge 48 candidates (one per lane) via 12 lex-min pop rounds
    if (w == 0) {
        float cd = (lane < 48) ? sd[lane] : 1e30f;
        int cix = (lane < 48) ? si[lane] : 0x7fffffff;
#pragma unroll
        for (int r = 0; r < KNN_K; ++r) {
            float mv = cd;
            int mi = cix;
#pragma unroll
            for (int off = 1; off < 64; off <<= 1) {
                float ov = __shfl_xor(mv, off);
                int oi = __shfl_xor(mi, off);
                if (ov < mv || (ov == mv && oi < mi)) { mv = ov; mi = oi; }
            }
            if (lane == 0) out[r] = mi;
            if (cix == mi) cd = 1e30f;  // pop (point indices unique across disjoint ranges)
        }
    }
}

// ---------------- gather -> bf16 A matrix ----------------
// A is [512 points * 16 rows][D]; rows 12..15 of each point zeroed.
__global__ __launch_bounds__(64) void gather_kernel(const float* __restrict__ feat,
                                                    const int* __restrict__ idx,
                                                    ushort_t* __restrict__ A, int D) {
    int row = blockIdx.x;  // 0..8191
    int p = row >> 4, k = row & 15;
    int tid = threadIdx.x;
    int n4 = D >> 2;
    ushort4* a4 = reinterpret_cast<ushort4*>(A + (size_t)row * D);
    if (k < KNN_K) {
        int src = idx[p * KNN_K + k];
        int b = p >> 5;
        const float4* f4 = reinterpret_cast<const float4*>(feat + ((size_t)b * NPTS + src) * D);
        for (int j = tid; j < n4; j += 64) {
            float4 v = f4[j];
            ushort4 u;
            u.x = f2bf(v.x); u.y = f2bf(v.y); u.z = f2bf(v.z); u.w = f2bf(v.w);
            a4[j] = u;
        }
    } else {
        ushort4 z; z.x = 0; z.y = 0; z.z = 0; z.w = 0;
        for (int j = tid; j < n4; j += 64) a4[j] = z;
    }
}

// ---------------- MFMA GEMM + BN/ReLU/max epilogue ----------------
// Block: 4 waves; M-tile = 8 points (128 rows), N-tile = 256 (64 per wave).
// A frag: lane holds A[m=lane&15][k=(lane>>4)*8+e]; B frag: W[o=lane&15][same k] (B=W^T).
// C/D: col=lane&15, row=(lane>>4)*4+reg (m89-verified). Pad rows 12..15 excluded via -inf.
template <int KD>
__global__ __launch_bounds__(256) void gemm_kernel(const ushort_t* __restrict__ A,
                                                   const ushort_t* __restrict__ Wb,
                                                   const float* __restrict__ bias,
                                                   const float* __restrict__ gamma,
                                                   const float* __restrict__ beta,
                                                   const float* __restrict__ mean,
                                                   const float* __restrict__ var,
                                                   float* __restrict__ out) {
    int tid = threadIdx.x;
    int w = tid >> 6, lane = tid & 63;
    int p0 = blockIdx.x * 8;
    int o_wave = blockIdx.y * 256 + w * 64;
    int lrow = lane & 15, kgrp = lane >> 4;

    f32x4 acc[8][4];
#pragma unroll
    for (int mi = 0; mi < 8; ++mi)
#pragma unroll
        for (int ni = 0; ni < 4; ++ni) {
            f32x4 z = {0.f, 0.f, 0.f, 0.f};
            acc[mi][ni] = z;
        }

    for (int kk = 0; kk < KD / 32; ++kk) {
        int k0 = kk * 32;
        bf16x8 a[8];
#pragma unroll
        for (int mi = 0; mi < 8; ++mi) {
            const ushort_t* ap = A + ((size_t)(p0 + mi) * 16 + lrow) * KD + k0 + kgrp * 8;
            a[mi] = *reinterpret_cast<const bf16x8*>(ap);
        }
#pragma unroll
        for (int ni = 0; ni < 4; ++ni) {
            const ushort_t* bp = Wb + (size_t)(o_wave + ni * 16 + lrow) * KD + k0 + kgrp * 8;
            bf16x8 bf = *reinterpret_cast<const bf16x8*>(bp);
#pragma unroll
            for (int mi = 0; mi < 8; ++mi)
                acc[mi][ni] = __builtin_amdgcn_mfma_f32_16x16x32_bf16(a[mi], bf, acc[mi][ni], 0, 0, 0);
        }
    }

    // epilogue: y = acc*sc + shift ; relu ; max over rows 0..11 ; store
#pragma unroll
    for (int ni = 0; ni < 4; ++ni) {
        int o = o_wave + ni * 16 + lrow;
        float sc = gamma[o] / sqrtf(var[o] + 1e-5f);
        float sh = (bias[o] - mean[o]) * sc + beta[o];
#pragma unroll
        for (int mi = 0; mi < 8; ++mi) {
            float m;
            if (kgrp < 3) {
                float y0 = fmaxf(acc[mi][ni][0] * sc + sh, 0.0f);
                float y1 = fmaxf(acc[mi][ni][1] * sc + sh, 0.0f);
                float y2 = fmaxf(acc[mi][ni][2] * sc + sh, 0.0f);
                float y3 = fmaxf(acc[mi][ni][3] * sc + sh, 0.0f);
                m = fmaxf(fmaxf(y0, y1), fmaxf(y2, y3));
            } else {
                m = -1e30f;  // pad rows 12..15
            }
            m = fmaxf(m, __shfl_xor(m, 16));
            m = fmaxf(m, __shfl_xor(m, 32));
            if (kgrp == 0) out[(size_t)(p0 + mi) * DOUT + o] = m;
        }
    }
}

extern "C" void kernel_launch(void* const* d_in, const int* in_sizes, int n_in,
                              void* d_out, int out_size, void* d_ws, size_t ws_size,
                              hipStream_t stream) {
    const float* feature_s = (const float*)d_in[0];
    const float* xyz_s     = (const float*)d_in[1];
    const float* feature_t = (const float*)d_in[2];
    const float* xyz_t     = (const float*)d_in[3];
    const float* Ws        = (const float*)d_in[4];
    const float* bias_s    = (const float*)d_in[5];
    const float* gamma_s   = (const float*)d_in[6];
    const float* beta_s    = (const float*)d_in[7];
    const float* mean_s    = (const float*)d_in[8];
    const float* var_s     = (const float*)d_in[9];
    const float* Wt        = (const float*)d_in[10];
    const float* bias_t    = (const float*)d_in[11];
    const float* gamma_t   = (const float*)d_in[12];
    const float* beta_t    = (const float*)d_in[13];
    const float* mean_t    = (const float*)d_in[14];
    const float* var_t     = (const float*)d_in[15];
    float* out = (float*)d_out;

    char* ws = (char*)d_ws;
    float* new_xyz  = (float*)(ws + 0);
    int* idx_s      = (int*)(ws + 8192);
    int* idx_t      = (int*)(ws + 32768);
    ushort_t* Wb_s  = (ushort_t*)(ws + 57344);
    ushort_t* Wb_t  = (ushort_t*)(ws + 581632);
    ushort_t* A     = (ushort_t*)(ws + 2678784);

    convw_kernel<<<1024, 256, 0, stream>>>(Wt, Wb_t, (1024 * 1024) / 4);
    convw_kernel<<<256, 256, 0, stream>>>(Ws, Wb_s, (1024 * 256) / 4);
    fps_kernel<<<16, 512, 0, stream>>>(xyz_t, new_xyz);
    knn_kernel<<<dim3(512, 2), 256, 0, stream>>>(xyz_s, xyz_t, new_xyz, idx_s, idx_t);

    gather_kernel<<<8192, 64, 0, stream>>>(feature_s, idx_s, A, DS);
    gemm_kernel<DS><<<dim3(64, 4), 256, 0, stream>>>(A, Wb_s, bias_s, gamma_s, beta_s,
                                                     mean_s, var_s, out);
    gather_kernel<<<8192, 64, 0, stream>>>(feature_t, idx_t, A, DT);
    gemm_kernel<DT><<<dim3(64, 4), 256, 0, stream>>>(A, Wb_t, bias_t, gamma_t, beta_t,
                                                     mean_t, var_t, out + (size_t)512 * 1024);
}